// Round 9
// baseline (28.704 us; speedup 1.0000x reference)
//
#include <hip/hip_runtime.h>

#define EPS 1e-5f

typedef short s8v __attribute__((ext_vector_type(8)));   // 8 bf16 in 4 VGPRs
typedef float f4v __attribute__((ext_vector_type(4)));

static __device__ inline short f2bf(float f) {
  return __builtin_bit_cast(short, (__bf16)f);
}

// workspace layout (float offsets)
#define OFF_SP    0                       // Spart[256]  (64 groups x 4 partials)
#define OFF_S2P   256                     // S2part[256]
#define OFF_WCB   512                     // bf16[384*128] = 24576 float slots
#define OFF_BC    (OFF_WCB + 24576)       // 384
#define OFF_QB    (OFF_BC + 384)          // bf16 [8][4096][32]
#define OFF_KB    (OFF_QB + 524288)
#define OFF_VTB   (OFF_KB + 524288)       // bf16 [8][32][4096] (transposed)
#define OFF_WOB   (OFF_VTB + 524288)      // bf16 [128][128]

// KP: blocks 0..63 = weight prep; blocks 64..319 = GN partial sums (atomic-free:
// each (group, quarter) writes its own slot; k2 finalizes).
__global__ __launch_bounds__(256) void kP(
    const float* __restrict__ wq, const float* __restrict__ bq,
    const float* __restrict__ wk, const float* __restrict__ bk,
    const float* __restrict__ wv, const float* __restrict__ bv,
    const float* __restrict__ wo, const float* __restrict__ x,
    short* __restrict__ Wcb, float* __restrict__ bc,
    short* __restrict__ WoB, float* __restrict__ Spart, float* __restrict__ S2part) {
  int blk = blockIdx.x;
  int tid = threadIdx.x;
  if (blk < 64) {
    int t = blk * 256 + tid;                // 0..16383
    const float qs = 0.17677669529663687f;  // 1/sqrt(32)
    Wcb[t]         = f2bf(wq[t] * qs);
    Wcb[16384 + t] = f2bf(wk[t]);
    Wcb[32768 + t] = f2bf(wv[t]);
    WoB[t]         = f2bf(wo[t]);
    if (t < 128) {
      bc[t]       = bq[t] * qs;
      bc[128 + t] = bk[t];
      bc[256 + t] = bv[t];
    }
  } else {
    int idx = blk - 64;                     // 0..255
    int g = idx >> 2, part = idx & 3;       // group 0..63, quarter 0..3
    const float4* xp = (const float4*)(x + (size_t)g * 16384 + part * 4096);
    float s = 0.f, s2 = 0.f;
    #pragma unroll
    for (int i = 0; i < 4; i++) {
      float4 v = xp[tid + i * 256];
      s  += v.x + v.y + v.z + v.w;
      s2 += v.x*v.x + v.y*v.y + v.z*v.z + v.w*v.w;
    }
    #pragma unroll
    for (int o = 32; o; o >>= 1) {
      s  += __shfl_down(s, o, 64);
      s2 += __shfl_down(s2, o, 64);
    }
    __shared__ float ls[4], ls2[4];
    int wid = tid >> 6, lane = tid & 63;
    if (!lane) { ls[wid] = s; ls2[wid] = s2; }
    __syncthreads();
    if (tid == 0) {
      float S = 0.f, S2 = 0.f;
      #pragma unroll
      for (int i = 0; i < 4; i++) { S += ls[i]; S2 += ls2[i]; }
      Spart[idx]  = S;
      S2part[idx] = S2;
    }
  }
}

// K2: GN finalize + affine + QKV projection via MFMA; outputs bf16. (unchanged)
__global__ __launch_bounds__(256) void k2_qkv(
    const float* __restrict__ x,
    const float* __restrict__ Spart, const float* __restrict__ S2part,
    const float* __restrict__ gw, const float* __restrict__ gb,
    const short* __restrict__ Wcb, const float* __restrict__ bc,
    short* __restrict__ qb, short* __restrict__ kb, short* __restrict__ vtb) {
  __shared__ short xn[64][136];
  __shared__ short WL[192][136];
  __shared__ float bcs[192];
  __shared__ float sm_s[128], sm_t[128];
  int bid    = blockIdx.x;          // 0..255
  int ptile  = bid >> 1, nslice = bid & 1;
  int b      = ptile >> 6;
  int pbase  = (ptile & 63) * 64;
  int nbase  = nslice * 192;
  int tid    = threadIdx.x;
  int w      = __builtin_amdgcn_readfirstlane(tid >> 6);
  int lane   = tid & 63;

  // issue all x loads into registers (latency hides under staging below)
  float va[16], vb[16];
  #pragma unroll
  for (int i = 0; i < 16; i++) {
    int c0 = (w + i * 4) * 2;
    va[i] = x[((size_t)(b * 128 + c0))     * 4096 + pbase + lane];
    vb[i] = x[((size_t)(b * 128 + c0 + 1)) * 4096 + pbase + lane];
  }
  // GN finalize -> per-channel affine in LDS
  if (tid < 128) {
    int c = tid, gi = (b * 32 + (c >> 2)) * 4;
    float S  = Spart[gi]  + Spart[gi + 1]  + Spart[gi + 2]  + Spart[gi + 3];
    float S2 = S2part[gi] + S2part[gi + 1] + S2part[gi + 2] + S2part[gi + 3];
    float mean = S * (1.f / 16384.f);
    float var  = S2 * (1.f / 16384.f) - mean * mean;
    float sv   = rsqrtf(var + EPS) * gw[c];
    sm_s[c] = sv;
    sm_t[c] = gb[c] - mean * sv;
  }
  // stage weights + biases
  #pragma unroll
  for (int i = 0; i < 12; i++) {
    int cc = tid + i * 256;          // 0..3071
    int row = cc >> 4, c8 = (cc & 15) * 8;
    *(s8v*)&WL[row][c8] = *(const s8v*)&Wcb[(nbase + row) * 128 + c8];
  }
  if (tid < 192) bcs[tid] = bc[nbase + tid];
  __syncthreads();   // affine visible

  // pack x tile to bf16 LDS
  #pragma unroll
  for (int i = 0; i < 16; i++) {
    int c0 = (w + i * 4) * 2;
    ushort e0 = (ushort)f2bf(fmaf(va[i], sm_s[c0],     sm_t[c0]));
    ushort e1 = (ushort)f2bf(fmaf(vb[i], sm_s[c0 + 1], sm_t[c0 + 1]));
    *(uint*)&xn[lane][c0] = ((uint)e1 << 16) | e0;
  }
  __syncthreads();   // xn/WL visible

  int l15 = lane & 15, kh = lane >> 4;
  f4v acc[12];
  #pragma unroll
  for (int nt = 0; nt < 12; nt++) acc[nt] = (f4v){0.f, 0.f, 0.f, 0.f};
  #pragma unroll
  for (int ks = 0; ks < 4; ks++) {
    s8v a = *(s8v*)&xn[w * 16 + l15][ks * 32 + kh * 8];
    #pragma unroll
    for (int nt = 0; nt < 12; nt++) {
      s8v wf = *(s8v*)&WL[nt * 16 + l15][ks * 32 + kh * 8];
      if (nbase + nt * 16 < 256)    // q/k tile: swapped operands
        acc[nt] = __builtin_amdgcn_mfma_f32_16x16x32_bf16(wf, a, acc[nt], 0, 0, 0);
      else                           // v tile
        acc[nt] = __builtin_amdgcn_mfma_f32_16x16x32_bf16(a, wf, acc[nt], 0, 0, 0);
    }
  }
  #pragma unroll
  for (int nt = 0; nt < 12; nt++) {
    if (nbase + nt * 16 < 256) {
      int ob  = nt * 16 + kh * 4;
      int o0i = nbase + ob;
      int hd  = (o0i & 127) >> 5, d0 = o0i & 31;
      int bh2 = b * 4 + hd;
      int px  = pbase + w * 16 + l15;
      short* dst = (o0i >> 7) ? kb : qb;
      ushort e0 = (ushort)f2bf(acc[nt][0] + bcs[ob + 0]);
      ushort e1 = (ushort)f2bf(acc[nt][1] + bcs[ob + 1]);
      ushort e2 = (ushort)f2bf(acc[nt][2] + bcs[ob + 2]);
      ushort e3 = (ushort)f2bf(acc[nt][3] + bcs[ob + 3]);
      uint2 pk = make_uint2(((uint)e1 << 16) | e0, ((uint)e3 << 16) | e2);
      *(uint2*)&dst[((size_t)bh2 * 4096 + px) * 32 + d0] = pk;
    } else {
      int o   = nbase + nt * 16 + l15;
      int hd  = (o & 127) >> 5, d = o & 31;
      int bh2 = b * 4 + hd;
      int px0 = pbase + w * 16 + kh * 4;
      float bias = bcs[nt * 16 + l15];
      ushort s0 = (ushort)f2bf(acc[nt][0] + bias);
      ushort s1 = (ushort)f2bf(acc[nt][1] + bias);
      ushort s2 = (ushort)f2bf(acc[nt][2] + bias);
      ushort s3 = (ushort)f2bf(acc[nt][3] + bias);
      uint2 pk2 = make_uint2(((uint)s1 << 16) | s0, ((uint)s3 << 16) | s2);
      *(uint2*)&vtb[((size_t)bh2 * 32 + d) * 4096 + px0] = pk2;
    }
  }
}

// K3: MFMA neighborhood attention + fused out-projection.
// 512 blocks x 256 threads (1 query row each), LDS 63 KB -> 2 blocks/CU.
// Wo held in per-wave registers (loaded at start, overlaps staging).
// Two-pass row processing: pass A = all 14 QK MFMAs into regs (pipelined);
// pass B = exp/pack/PV per row. Attention tile unions onto dead P buffer.
__global__ __launch_bounds__(256, 2) void k3_attn_proj(
    const short* __restrict__ qb, const short* __restrict__ kb, const short* __restrict__ vtb,
    const float* __restrict__ rpb, const short* __restrict__ WoB,
    const float* __restrict__ bo, float* __restrict__ out) {
  __shared__ ushort K_s[7][64][32];      // 28.7 KB
  __shared__ ushort VT_s[7][32][68];     // 30.5 KB
  __shared__ ushort PT_s[4][16][36];     // 4.6 KB; attention tile [16][132] overlays
  __shared__ float  rpb_s[176];

  int lb   = blockIdx.x;            // 0..511
  int bh   = lb & 7;                // XCD swizzle: each XCD owns one bh
  int y    = lb >> 3;               // 0..63
  int head = bh & 3, b = bh >> 2;
  int tid  = threadIdx.x;
  int w    = __builtin_amdgcn_readfirstlane(tid >> 6);  // 0..3
  int lane = tid & 63, l15 = lane & 15, kh = lane >> 4;
  int ys   = min(max(y - 3, 0), 57);

  int c0  = w * 8 + (w >> 1) * 8;   // strip col window start: 0,8,24,32
  int xq  = w * 16 + l15;           // query x
  // Wo fragments into registers (global loads overlap LDS staging below)
  s8v wof[2][4];
  #pragma unroll
  for (int nt = 0; nt < 2; nt++)
    #pragma unroll
    for (int ks = 0; ks < 4; ks++)
      wof[nt][ks] = *(const s8v*)&WoB[(w * 32 + nt * 16 + l15) * 128 + ks * 32 + kh * 8];
  s8v qf = *(const s8v*)&qb[((size_t)bh * 4096 + y * 64 + xq) * 32 + kh * 8];

  // stage K window (7 rows x 64 col x 32 ch bf16)
  {
    const size_t kbase = (size_t)bh * 4096 * 32;
    #pragma unroll
    for (int i = 0; i < 7; i++) {
      int cc = tid + i * 256;
      int row = cc >> 8, rem = cc & 255;
      int col = rem >> 2, ch8 = (rem & 3) * 8;
      *(s8v*)&K_s[row][col][ch8] =
          *(const s8v*)&kb[kbase + (size_t)((ys + row) * 64 + col) * 32 + ch8];
    }
  }
  // stage VT window (7 rows x 32 d x 64 px bf16)
  {
    const size_t vbase = (size_t)bh * 32 * 4096;
    #pragma unroll
    for (int i = 0; i < 7; i++) {
      int cc = tid + i * 256;
      int row = cc >> 8, rem = cc & 255;
      int d = rem >> 3, c8 = (rem & 7) * 8;
      *(s8v*)&VT_s[row][d][c8] =
          *(const s8v*)&vtb[vbase + (size_t)d * 4096 + (ys + row) * 64 + c8];
    }
  }
  if (tid < 169) rpb_s[tid] = rpb[head * 169 + tid];
  __syncthreads();

  int xs  = min(max(xq - 3, 0), 57);
  int pbw = 3 + max(3 - xq, 0) + min(60 - xq, 0);
  int pbh = 3 + max(3 - y, 0) + min(60 - y, 0);

  int   bidx[8];
  float badd[8];
  #pragma unroll
  for (int j = 0; j < 8; ++j) {
    int cc = (j >> 2) * 16 + kh * 4 + (j & 3);
    int dx = c0 + cc - xs;
    bool valid = (dx >= 0) && (dx < 7);
    bidx[j] = pbw + min(max(dx, 0), 6);
    badd[j] = valid ? 0.f : -1e30f;
  }

  const f4v zero = {0.f, 0.f, 0.f, 0.f};

  // pass A: all QK^T MFMAs (independent -> pipelined)
  f4v lg0[7], lg1[7];
  #pragma unroll
  for (int row = 0; row < 7; ++row) {
    s8v ka0 = *(s8v*)&K_s[row][c0 + l15][kh * 8];
    s8v ka1 = *(s8v*)&K_s[row][c0 + 16 + l15][kh * 8];
    lg0[row] = __builtin_amdgcn_mfma_f32_16x16x32_bf16(ka0, qf, zero, 0, 0, 0);
    lg1[row] = __builtin_amdgcn_mfma_f32_16x16x32_bf16(ka1, qf, zero, 0, 0, 0);
  }

  // pass B: exp / pack / PV per row
  f4v o0 = zero, o1 = zero;
  float ssum = 0.f;
  #pragma unroll
  for (int row = 0; row < 7; ++row) {
    int rbase = (pbh + row) * 13;
    float p[8];
    #pragma unroll
    for (int j = 0; j < 4; ++j) {
      p[j]     = __expf(lg0[row][j] + rpb_s[rbase + bidx[j]]     + badd[j]);
      p[j + 4] = __expf(lg1[row][j] + rpb_s[rbase + bidx[j + 4]] + badd[j + 4]);
      ssum += p[j] + p[j + 4];
    }
    uint u0 = ((uint)(ushort)f2bf(p[1]) << 16) | (ushort)f2bf(p[0]);
    uint u1 = ((uint)(ushort)f2bf(p[3]) << 16) | (ushort)f2bf(p[2]);
    uint u2 = ((uint)(ushort)f2bf(p[5]) << 16) | (ushort)f2bf(p[4]);
    uint u3 = ((uint)(ushort)f2bf(p[7]) << 16) | (ushort)f2bf(p[6]);
    *(uint2*)&PT_s[w][l15][kh * 4]      = make_uint2(u0, u1);
    *(uint2*)&PT_s[w][l15][16 + kh * 4] = make_uint2(u2, u3);
    s8v pa  = *(s8v*)&PT_s[w][l15][kh * 8];
    s8v vt0 = *(s8v*)&VT_s[row][l15][c0 + kh * 8];
    s8v vt1 = *(s8v*)&VT_s[row][16 + l15][c0 + kh * 8];
    o0 = __builtin_amdgcn_mfma_f32_16x16x32_bf16(pa, vt0, o0, 0, 0, 0);
    o1 = __builtin_amdgcn_mfma_f32_16x16x32_bf16(pa, vt1, o1, 0, 0, 0);
  }

  ssum += __shfl_xor(ssum, 16, 64);
  ssum += __shfl_xor(ssum, 32, 64);

  __syncthreads();   // all waves done with P -> overlay attention tile

  // write attention tile (scrambled space): px-col = w*4+kh, c' = r*32 + d
  ushort* tile = (ushort*)PT_s;      // [16][132]
  {
    int col = w * 4 + kh;
    #pragma unroll
    for (int r = 0; r < 4; ++r) {
      float sq = __builtin_bit_cast(float,
          __builtin_amdgcn_ds_bpermute((kh * 4 + r) << 2, __builtin_bit_cast(int, ssum)));
      float inv = 1.f / sq;
      tile[col * 132 + r * 32 + l15]      = (ushort)f2bf(o0[r] * inv);
      tile[col * 132 + r * 32 + 16 + l15] = (ushort)f2bf(o1[r] * inv);
    }
  }
  __syncthreads();

  // out-projection from registers: wave w owns outputs o = w*32 + nt*16 + l15
  f4v acc2[2];
  acc2[0] = zero; acc2[1] = zero;
  #pragma unroll
  for (int ks = 0; ks < 4; ks++) {
    s8v a = *(s8v*)&tile[l15 * 132 + ks * 32 + kh * 8];
    #pragma unroll
    for (int nt = 0; nt < 2; nt++)
      acc2[nt] = __builtin_amdgcn_mfma_f32_16x16x32_bf16(a, wof[nt][ks], acc2[nt], 0, 0, 0);
  }
  int pxg = (head * 16 + (y >> 2)) * 64 + ((y & 3) << 4);
  #pragma unroll
  for (int nt = 0; nt < 2; nt++) {
    int o = w * 32 + nt * 16 + l15;
    float bias = bo[o];
    float4 val = make_float4(acc2[nt][0] + bias, acc2[nt][1] + bias,
                             acc2[nt][2] + bias, acc2[nt][3] + bias);
    *(float4*)&out[((size_t)b * 128 + o) * 4096 + pxg + kh * 4] = val;
  }
}

extern "C" void kernel_launch(void* const* d_in, const int* in_sizes, int n_in,
                              void* d_out, int out_size, void* d_ws, size_t ws_size,
                              hipStream_t stream) {
  (void)in_sizes; (void)n_in; (void)out_size; (void)ws_size;
  const float* x   = (const float*)d_in[0];
  const float* gw  = (const float*)d_in[1];
  const float* gb  = (const float*)d_in[2];
  const float* wq  = (const float*)d_in[3];
  const float* bq  = (const float*)d_in[4];
  const float* wk  = (const float*)d_in[5];
  const float* bk  = (const float*)d_in[6];
  const float* wv  = (const float*)d_in[7];
  const float* bv  = (const float*)d_in[8];
  const float* wo  = (const float*)d_in[9];
  const float* bo  = (const float*)d_in[10];
  const float* rpb = (const float*)d_in[11];
  float* ws     = (float*)d_ws;
  float* Spart  = ws + OFF_SP;
  float* S2part = ws + OFF_S2P;
  short* Wcb    = (short*)(ws + OFF_WCB);
  float* bc     = ws + OFF_BC;
  short* qb     = (short*)(ws + OFF_QB);
  short* kb     = (short*)(ws + OFF_KB);
  short* vtb    = (short*)(ws + OFF_VTB);
  short* WoB    = (short*)(ws + OFF_WOB);
  float* out    = (float*)d_out;

  hipLaunchKernelGGL(kP, dim3(320), dim3(256), 0, stream,
                     wq, bq, wk, bk, wv, bv, wo, x, Wcb, bc, WoB, Spart, S2part);
  hipLaunchKernelGGL(k2_qkv, dim3(256), dim3(256), 0, stream,
                     x, Spart, S2part, gw, gb, Wcb, bc, qb, kb, vtb);
  hipLaunchKernelGGL(k3_attn_proj, dim3(512), dim3(256), 0, stream,
                     qb, kb, vtb, rpb, WoB, bo, out);
}

// Round 10
// 27.862 us; speedup vs baseline: 1.0302x; 1.0302x over previous
//
#include <hip/hip_runtime.h>

#define EPS 1e-5f

typedef short s8v __attribute__((ext_vector_type(8)));   // 8 bf16 in 4 VGPRs
typedef float f4v __attribute__((ext_vector_type(4)));

static __device__ inline short f2bf(float f) {
  return __builtin_bit_cast(short, (__bf16)f);
}

// workspace layout (float offsets)
#define OFF_SP    0                       // Spart[256]  (64 groups x 4 partials)
#define OFF_S2P   256                     // S2part[256]
#define OFF_WCB   512                     // bf16[384*128] = 24576 float slots
#define OFF_BC    (OFF_WCB + 24576)       // 384
#define OFF_QB    (OFF_BC + 384)          // bf16 [8][4096][32]
#define OFF_KB    (OFF_QB + 524288)
#define OFF_VTB   (OFF_KB + 524288)       // bf16 [8][32][4096] (transposed)
#define OFF_WOB   (OFF_VTB + 524288)      // bf16 [128][128]

// KP: blocks 0..63 = weight prep; blocks 64..319 = GN partial sums (atomic-free:
// each (group, quarter) writes its own slot; k2 finalizes).
__global__ __launch_bounds__(256) void kP(
    const float* __restrict__ wq, const float* __restrict__ bq,
    const float* __restrict__ wk, const float* __restrict__ bk,
    const float* __restrict__ wv, const float* __restrict__ bv,
    const float* __restrict__ wo, const float* __restrict__ x,
    short* __restrict__ Wcb, float* __restrict__ bc,
    short* __restrict__ WoB, float* __restrict__ Spart, float* __restrict__ S2part) {
  int blk = blockIdx.x;
  int tid = threadIdx.x;
  if (blk < 64) {
    int t = blk * 256 + tid;                // 0..16383
    const float qs = 0.17677669529663687f;  // 1/sqrt(32)
    Wcb[t]         = f2bf(wq[t] * qs);
    Wcb[16384 + t] = f2bf(wk[t]);
    Wcb[32768 + t] = f2bf(wv[t]);
    WoB[t]         = f2bf(wo[t]);
    if (t < 128) {
      bc[t]       = bq[t] * qs;
      bc[128 + t] = bk[t];
      bc[256 + t] = bv[t];
    }
  } else {
    int idx = blk - 64;                     // 0..255
    int g = idx >> 2, part = idx & 3;       // group 0..63, quarter 0..3
    const float4* xp = (const float4*)(x + (size_t)g * 16384 + part * 4096);
    float s = 0.f, s2 = 0.f;
    #pragma unroll
    for (int i = 0; i < 4; i++) {
      float4 v = xp[tid + i * 256];
      s  += v.x + v.y + v.z + v.w;
      s2 += v.x*v.x + v.y*v.y + v.z*v.z + v.w*v.w;
    }
    #pragma unroll
    for (int o = 32; o; o >>= 1) {
      s  += __shfl_down(s, o, 64);
      s2 += __shfl_down(s2, o, 64);
    }
    __shared__ float ls[4], ls2[4];
    int wid = tid >> 6, lane = tid & 63;
    if (!lane) { ls[wid] = s; ls2[wid] = s2; }
    __syncthreads();
    if (tid == 0) {
      float S = 0.f, S2 = 0.f;
      #pragma unroll
      for (int i = 0; i < 4; i++) { S += ls[i]; S2 += ls2[i]; }
      Spart[idx]  = S;
      S2part[idx] = S2;
    }
  }
}

// K2: GN finalize + affine + QKV projection via MFMA; outputs bf16. (unchanged)
__global__ __launch_bounds__(256) void k2_qkv(
    const float* __restrict__ x,
    const float* __restrict__ Spart, const float* __restrict__ S2part,
    const float* __restrict__ gw, const float* __restrict__ gb,
    const short* __restrict__ Wcb, const float* __restrict__ bc,
    short* __restrict__ qb, short* __restrict__ kb, short* __restrict__ vtb) {
  __shared__ short xn[64][136];
  __shared__ short WL[192][136];
  __shared__ float bcs[192];
  __shared__ float sm_s[128], sm_t[128];
  int bid    = blockIdx.x;          // 0..255
  int ptile  = bid >> 1, nslice = bid & 1;
  int b      = ptile >> 6;
  int pbase  = (ptile & 63) * 64;
  int nbase  = nslice * 192;
  int tid    = threadIdx.x;
  int w      = __builtin_amdgcn_readfirstlane(tid >> 6);
  int lane   = tid & 63;

  float va[16], vb[16];
  #pragma unroll
  for (int i = 0; i < 16; i++) {
    int c0 = (w + i * 4) * 2;
    va[i] = x[((size_t)(b * 128 + c0))     * 4096 + pbase + lane];
    vb[i] = x[((size_t)(b * 128 + c0 + 1)) * 4096 + pbase + lane];
  }
  if (tid < 128) {
    int c = tid, gi = (b * 32 + (c >> 2)) * 4;
    float S  = Spart[gi]  + Spart[gi + 1]  + Spart[gi + 2]  + Spart[gi + 3];
    float S2 = S2part[gi] + S2part[gi + 1] + S2part[gi + 2] + S2part[gi + 3];
    float mean = S * (1.f / 16384.f);
    float var  = S2 * (1.f / 16384.f) - mean * mean;
    float sv   = rsqrtf(var + EPS) * gw[c];
    sm_s[c] = sv;
    sm_t[c] = gb[c] - mean * sv;
  }
  #pragma unroll
  for (int i = 0; i < 12; i++) {
    int cc = tid + i * 256;          // 0..3071
    int row = cc >> 4, c8 = (cc & 15) * 8;
    *(s8v*)&WL[row][c8] = *(const s8v*)&Wcb[(nbase + row) * 128 + c8];
  }
  if (tid < 192) bcs[tid] = bc[nbase + tid];
  __syncthreads();   // affine visible

  #pragma unroll
  for (int i = 0; i < 16; i++) {
    int c0 = (w + i * 4) * 2;
    ushort e0 = (ushort)f2bf(fmaf(va[i], sm_s[c0],     sm_t[c0]));
    ushort e1 = (ushort)f2bf(fmaf(vb[i], sm_s[c0 + 1], sm_t[c0 + 1]));
    *(uint*)&xn[lane][c0] = ((uint)e1 << 16) | e0;
  }
  __syncthreads();   // xn/WL visible

  int l15 = lane & 15, kh = lane >> 4;
  f4v acc[12];
  #pragma unroll
  for (int nt = 0; nt < 12; nt++) acc[nt] = (f4v){0.f, 0.f, 0.f, 0.f};
  #pragma unroll
  for (int ks = 0; ks < 4; ks++) {
    s8v a = *(s8v*)&xn[w * 16 + l15][ks * 32 + kh * 8];
    #pragma unroll
    for (int nt = 0; nt < 12; nt++) {
      s8v wf = *(s8v*)&WL[nt * 16 + l15][ks * 32 + kh * 8];
      if (nbase + nt * 16 < 256)    // q/k tile: swapped operands
        acc[nt] = __builtin_amdgcn_mfma_f32_16x16x32_bf16(wf, a, acc[nt], 0, 0, 0);
      else                           // v tile
        acc[nt] = __builtin_amdgcn_mfma_f32_16x16x32_bf16(a, wf, acc[nt], 0, 0, 0);
    }
  }
  #pragma unroll
  for (int nt = 0; nt < 12; nt++) {
    if (nbase + nt * 16 < 256) {
      int ob  = nt * 16 + kh * 4;
      int o0i = nbase + ob;
      int hd  = (o0i & 127) >> 5, d0 = o0i & 31;
      int bh2 = b * 4 + hd;
      int px  = pbase + w * 16 + l15;
      short* dst = (o0i >> 7) ? kb : qb;
      ushort e0 = (ushort)f2bf(acc[nt][0] + bcs[ob + 0]);
      ushort e1 = (ushort)f2bf(acc[nt][1] + bcs[ob + 1]);
      ushort e2 = (ushort)f2bf(acc[nt][2] + bcs[ob + 2]);
      ushort e3 = (ushort)f2bf(acc[nt][3] + bcs[ob + 3]);
      uint2 pk = make_uint2(((uint)e1 << 16) | e0, ((uint)e3 << 16) | e2);
      *(uint2*)&dst[((size_t)bh2 * 4096 + px) * 32 + d0] = pk;
    } else {
      int o   = nbase + nt * 16 + l15;
      int hd  = (o & 127) >> 5, d = o & 31;
      int bh2 = b * 4 + hd;
      int px0 = pbase + w * 16 + kh * 4;
      float bias = bcs[nt * 16 + l15];
      ushort s0 = (ushort)f2bf(acc[nt][0] + bias);
      ushort s1 = (ushort)f2bf(acc[nt][1] + bias);
      ushort s2 = (ushort)f2bf(acc[nt][2] + bias);
      ushort s3 = (ushort)f2bf(acc[nt][3] + bias);
      uint2 pk2 = make_uint2(((uint)s1 << 16) | s0, ((uint)s3 << 16) | s2);
      *(uint2*)&vtb[((size_t)bh2 * 32 + d) * 4096 + px0] = pk2;
    }
  }
}

// K3: MFMA neighborhood attention + fused out-projection, 2 query rows per block
// (round-8 traffic shape), LDS trimmed to ~78 KB -> 2 blocks/CU (4 waves/SIMD):
// Wo in per-wave registers (load overlaps staging); attention tile overlays P_s.
__global__ __launch_bounds__(512, 4) void k3_attn_proj(
    const short* __restrict__ qb, const short* __restrict__ kb, const short* __restrict__ vtb,
    const float* __restrict__ rpb, const short* __restrict__ WoB,
    const float* __restrict__ bo, float* __restrict__ out) {
  __shared__ ushort K_s[8][64][32];      // 32 KB
  __shared__ ushort VT_s[8][32][68];     // 34 KB
  __shared__ ushort P_s[8][16][40];      // 10 KB; attention tile [2][16][136] overlays
  __shared__ float  rpb_s[176];

  int lb    = blockIdx.x;           // 0..255
  int bh    = lb & 7;               // XCD swizzle: each XCD owns one bh
  int chunk = lb >> 3;              // 0..31
  int y0    = chunk * 2;
  int head  = bh & 3, b = bh >> 2;
  int tid   = threadIdx.x;
  int w     = __builtin_amdgcn_readfirstlane(tid >> 6);  // 0..7
  int lane  = tid & 63, l15 = lane & 15, kh = lane >> 4;
  int wsub  = w & 3, rsel = w >> 2;
  int y     = y0 + rsel;
  int ys0   = min(max(y0 - 3, 0), 57);
  int ysoff = min(max(y - 3, 0), 57) - ys0;   // 0 or 1

  // Wo fragments into registers (global load latency hides under LDS staging)
  s8v wof[2][4];
  #pragma unroll
  for (int nt = 0; nt < 2; nt++)
    #pragma unroll
    for (int ks = 0; ks < 4; ks++)
      wof[nt][ks] = *(const s8v*)&WoB[(wsub * 32 + nt * 16 + l15) * 128 + ks * 32 + kh * 8];

  // stage K window (8 rows x 64 col x 32 ch bf16)
  {
    const size_t kbase = (size_t)bh * 4096 * 32;
    #pragma unroll
    for (int i = 0; i < 4; i++) {
      int cc = tid + i * 512;
      int row = cc >> 8, rem = cc & 255;
      int col = rem >> 2, ch8 = (rem & 3) * 8;
      int yr = min(ys0 + row, 63);
      *(s8v*)&K_s[row][col][ch8] = *(const s8v*)&kb[kbase + (size_t)(yr * 64 + col) * 32 + ch8];
    }
  }
  // stage VT window (8 rows x 32 d x 64 px bf16)
  {
    const size_t vbase = (size_t)bh * 32 * 4096;
    #pragma unroll
    for (int i = 0; i < 4; i++) {
      int cc = tid + i * 512;
      int row = cc >> 8, rem = cc & 255;
      int d = rem >> 3, c8 = (rem & 7) * 8;
      int yr = min(ys0 + row, 63);
      *(s8v*)&VT_s[row][d][c8] = *(const s8v*)&vtb[vbase + (size_t)d * 4096 + yr * 64 + c8];
    }
  }
  if (tid < 169) rpb_s[tid] = rpb[head * 169 + tid];
  __syncthreads();

  int c0  = wsub * 8 + (wsub >> 1) * 8;   // strip col window start: 0,8,24,32
  int xq  = wsub * 16 + l15;              // query x
  int xs  = min(max(xq - 3, 0), 57);
  int pbw = 3 + max(3 - xq, 0) + min(60 - xq, 0);
  int pbh = 3 + max(3 - y, 0) + min(60 - y, 0);

  s8v qf = *(const s8v*)&qb[((size_t)bh * 4096 + y * 64 + xq) * 32 + kh * 8];

  int   bidx[8];
  float badd[8];
  #pragma unroll
  for (int j = 0; j < 8; ++j) {
    int cc = (j >> 2) * 16 + kh * 4 + (j & 3);
    int dx = c0 + cc - xs;
    bool valid = (dx >= 0) && (dx < 7);
    bidx[j] = pbw + min(max(dx, 0), 6);
    badd[j] = valid ? 0.f : -1e30f;
  }

  const f4v zero = {0.f, 0.f, 0.f, 0.f};
  f4v o0 = zero, o1 = zero;
  float ssum = 0.f;

  #pragma unroll
  for (int row = 0; row < 7; ++row) {
    int kr = ysoff + row;
    s8v ka0 = *(s8v*)&K_s[kr][c0 + l15][kh * 8];
    s8v ka1 = *(s8v*)&K_s[kr][c0 + 16 + l15][kh * 8];
    f4v lg0 = __builtin_amdgcn_mfma_f32_16x16x32_bf16(ka0, qf, zero, 0, 0, 0);
    f4v lg1 = __builtin_amdgcn_mfma_f32_16x16x32_bf16(ka1, qf, zero, 0, 0, 0);
    int rbase = (pbh + row) * 13;
    float p[8];
    #pragma unroll
    for (int j = 0; j < 4; ++j) {
      p[j]     = __expf(lg0[j] + rpb_s[rbase + bidx[j]]     + badd[j]);
      p[j + 4] = __expf(lg1[j] + rpb_s[rbase + bidx[j + 4]] + badd[j + 4]);
      ssum += p[j] + p[j + 4];
    }
    uint u0 = ((uint)(ushort)f2bf(p[1]) << 16) | (ushort)f2bf(p[0]);
    uint u1 = ((uint)(ushort)f2bf(p[3]) << 16) | (ushort)f2bf(p[2]);
    uint u2 = ((uint)(ushort)f2bf(p[5]) << 16) | (ushort)f2bf(p[4]);
    uint u3 = ((uint)(ushort)f2bf(p[7]) << 16) | (ushort)f2bf(p[6]);
    *(uint2*)&P_s[w][l15][kh * 4]      = make_uint2(u0, u1);
    *(uint2*)&P_s[w][l15][16 + kh * 4] = make_uint2(u2, u3);
    s8v pa  = *(s8v*)&P_s[w][l15][kh * 8];
    s8v vt0 = *(s8v*)&VT_s[kr][l15][c0 + kh * 8];
    s8v vt1 = *(s8v*)&VT_s[kr][16 + l15][c0 + kh * 8];
    o0 = __builtin_amdgcn_mfma_f32_16x16x32_bf16(pa, vt0, o0, 0, 0, 0);
    o1 = __builtin_amdgcn_mfma_f32_16x16x32_bf16(pa, vt1, o1, 0, 0, 0);
  }

  ssum += __shfl_xor(ssum, 16, 64);
  ssum += __shfl_xor(ssum, 32, 64);

  __syncthreads();   // all waves done reading P_s -> overlay attention tile

  // write attention tile into overlay: row = rsel*16 + px-col, c' = r*32 + d
  ushort* tile = (ushort*)P_s;       // [2][16][136]
  {
    int col = wsub * 4 + kh;
    #pragma unroll
    for (int r = 0; r < 4; ++r) {
      float sq = __builtin_bit_cast(float,
          __builtin_amdgcn_ds_bpermute((kh * 4 + r) << 2, __builtin_bit_cast(int, ssum)));
      float inv = 1.f / sq;
      tile[(rsel * 16 + col) * 136 + r * 32 + l15]      = (ushort)f2bf(o0[r] * inv);
      tile[(rsel * 16 + col) * 136 + r * 32 + 16 + l15] = (ushort)f2bf(o1[r] * inv);
    }
  }
  __syncthreads();

  // out-projection from registers: wave (wsub,rsel) owns o = wsub*32 + nt*16 + l15
  f4v acc2[2];
  acc2[0] = zero; acc2[1] = zero;
  #pragma unroll
  for (int ks = 0; ks < 4; ks++) {
    s8v a = *(s8v*)&tile[(rsel * 16 + l15) * 136 + ks * 32 + kh * 8];
    #pragma unroll
    for (int nt = 0; nt < 2; nt++)
      acc2[nt] = __builtin_amdgcn_mfma_f32_16x16x32_bf16(a, wof[nt][ks], acc2[nt], 0, 0, 0);
  }
  int pxg = (head * 16 + (y >> 2)) * 64 + ((y & 3) << 4);
  #pragma unroll
  for (int nt = 0; nt < 2; nt++) {
    int o = wsub * 32 + nt * 16 + l15;
    float bias = bo[o];
    float4 val = make_float4(acc2[nt][0] + bias, acc2[nt][1] + bias,
                             acc2[nt][2] + bias, acc2[nt][3] + bias);
    *(float4*)&out[((size_t)b * 128 + o) * 4096 + pxg + kh * 4] = val;
  }
}

extern "C" void kernel_launch(void* const* d_in, const int* in_sizes, int n_in,
                              void* d_out, int out_size, void* d_ws, size_t ws_size,
                              hipStream_t stream) {
  (void)in_sizes; (void)n_in; (void)out_size; (void)ws_size;
  const float* x   = (const float*)d_in[0];
  const float* gw  = (const float*)d_in[1];
  const float* gb  = (const float*)d_in[2];
  const float* wq  = (const float*)d_in[3];
  const float* bq  = (const float*)d_in[4];
  const float* wk  = (const float*)d_in[5];
  const float* bk  = (const float*)d_in[6];
  const float* wv  = (const float*)d_in[7];
  const float* bv  = (const float*)d_in[8];
  const float* wo  = (const float*)d_in[9];
  const float* bo  = (const float*)d_in[10];
  const float* rpb = (const float*)d_in[11];
  float* ws     = (float*)d_ws;
  float* Spart  = ws + OFF_SP;
  float* S2part = ws + OFF_S2P;
  short* Wcb    = (short*)(ws + OFF_WCB);
  float* bc     = ws + OFF_BC;
  short* qb     = (short*)(ws + OFF_QB);
  short* kb     = (short*)(ws + OFF_KB);
  short* vtb    = (short*)(ws + OFF_VTB);
  short* WoB    = (short*)(ws + OFF_WOB);
  float* out    = (float*)d_out;

  hipLaunchKernelGGL(kP, dim3(320), dim3(256), 0, stream,
                     wq, bq, wk, bk, wv, bv, wo, x, Wcb, bc, WoB, Spart, S2part);
  hipLaunchKernelGGL(k2_qkv, dim3(256), dim3(256), 0, stream,
                     x, Spart, S2part, gw, gb, Wcb, bc, qb, kb, vtb);
  hipLaunchKernelGGL(k3_attn_proj, dim3(256), dim3(512), 0, stream,
                     qb, kb, vtb, rpb, WoB, bo, out);
}

// Round 11
// 27.097 us; speedup vs baseline: 1.0593x; 1.0282x over previous
//
#include <hip/hip_runtime.h>

#define EPS 1e-5f

typedef short s8v __attribute__((ext_vector_type(8)));   // 8 bf16 in 4 VGPRs
typedef float f4v __attribute__((ext_vector_type(4)));

static __device__ inline short f2bf(float f) {
  return __builtin_bit_cast(short, (__bf16)f);
}

// workspace layout (float offsets)
#define OFF_SP    0                       // Spart[256]  (64 groups x 4 partials)
#define OFF_S2P   256                     // S2part[256]
#define OFF_WCB   512                     // bf16[384*128] = 24576 float slots
#define OFF_BC    (OFF_WCB + 24576)       // 384
#define OFF_QB    (OFF_BC + 384)          // bf16 [8][4096][32]
#define OFF_KB    (OFF_QB + 524288)
#define OFF_VTB   (OFF_KB + 524288)       // bf16 [8][32][4096] (transposed)
#define OFF_WOB   (OFF_VTB + 524288)      // bf16 [128][128]

// KP: blocks 0..63 = weight prep; blocks 64..319 = GN partial sums (atomic-free:
// each (group, quarter) writes its own slot; k2 finalizes). (unchanged)
__global__ __launch_bounds__(256) void kP(
    const float* __restrict__ wq, const float* __restrict__ bq,
    const float* __restrict__ wk, const float* __restrict__ bk,
    const float* __restrict__ wv, const float* __restrict__ bv,
    const float* __restrict__ wo, const float* __restrict__ x,
    short* __restrict__ Wcb, float* __restrict__ bc,
    short* __restrict__ WoB, float* __restrict__ Spart, float* __restrict__ S2part) {
  int blk = blockIdx.x;
  int tid = threadIdx.x;
  if (blk < 64) {
    int t = blk * 256 + tid;                // 0..16383
    const float qs = 0.17677669529663687f;  // 1/sqrt(32)
    Wcb[t]         = f2bf(wq[t] * qs);
    Wcb[16384 + t] = f2bf(wk[t]);
    Wcb[32768 + t] = f2bf(wv[t]);
    WoB[t]         = f2bf(wo[t]);
    if (t < 128) {
      bc[t]       = bq[t] * qs;
      bc[128 + t] = bk[t];
      bc[256 + t] = bv[t];
    }
  } else {
    int idx = blk - 64;                     // 0..255
    int g = idx >> 2, part = idx & 3;       // group 0..63, quarter 0..3
    const float4* xp = (const float4*)(x + (size_t)g * 16384 + part * 4096);
    float s = 0.f, s2 = 0.f;
    #pragma unroll
    for (int i = 0; i < 4; i++) {
      float4 v = xp[tid + i * 256];
      s  += v.x + v.y + v.z + v.w;
      s2 += v.x*v.x + v.y*v.y + v.z*v.z + v.w*v.w;
    }
    #pragma unroll
    for (int o = 32; o; o >>= 1) {
      s  += __shfl_down(s, o, 64);
      s2 += __shfl_down(s2, o, 64);
    }
    __shared__ float ls[4], ls2[4];
    int wid = tid >> 6, lane = tid & 63;
    if (!lane) { ls[wid] = s; ls2[wid] = s2; }
    __syncthreads();
    if (tid == 0) {
      float S = 0.f, S2 = 0.f;
      #pragma unroll
      for (int i = 0; i < 4; i++) { S += ls[i]; S2 += ls2[i]; }
      Spart[idx]  = S;
      S2part[idx] = S2;
    }
  }
}

// K2: GN finalize + affine + QKV projection via MFMA; outputs bf16.
// 512 blocks = 128 pixel-tiles x 4 n-slices (96 outputs) -> 43 KB LDS, 2 blocks/CU
// (2 waves/SIMD: staging of one block overlaps MFMA of the other).
__global__ __launch_bounds__(256) void k2_qkv(
    const float* __restrict__ x,
    const float* __restrict__ Spart, const float* __restrict__ S2part,
    const float* __restrict__ gw, const float* __restrict__ gb,
    const short* __restrict__ Wcb, const float* __restrict__ bc,
    short* __restrict__ qb, short* __restrict__ kb, short* __restrict__ vtb) {
  __shared__ short xn[64][136];
  __shared__ short WL[96][136];
  __shared__ float bcs[96];
  __shared__ float sm_s[128], sm_t[128];
  int bid    = blockIdx.x;          // 0..511
  int ptile  = bid >> 2, nslice = bid & 3;
  int b      = ptile >> 6;
  int pbase  = (ptile & 63) * 64;
  int nbase  = nslice * 96;
  int tid    = threadIdx.x;
  int w      = __builtin_amdgcn_readfirstlane(tid >> 6);
  int lane   = tid & 63;

  // issue all x loads into registers (latency hides under staging below)
  float va[16], vb[16];
  #pragma unroll
  for (int i = 0; i < 16; i++) {
    int c0 = (w + i * 4) * 2;
    va[i] = x[((size_t)(b * 128 + c0))     * 4096 + pbase + lane];
    vb[i] = x[((size_t)(b * 128 + c0 + 1)) * 4096 + pbase + lane];
  }
  // GN finalize -> per-channel affine in LDS
  if (tid < 128) {
    int c = tid, gi = (b * 32 + (c >> 2)) * 4;
    float S  = Spart[gi]  + Spart[gi + 1]  + Spart[gi + 2]  + Spart[gi + 3];
    float S2 = S2part[gi] + S2part[gi + 1] + S2part[gi + 2] + S2part[gi + 3];
    float mean = S * (1.f / 16384.f);
    float var  = S2 * (1.f / 16384.f) - mean * mean;
    float sv   = rsqrtf(var + EPS) * gw[c];
    sm_s[c] = sv;
    sm_t[c] = gb[c] - mean * sv;
  }
  // stage weight slice + biases
  #pragma unroll
  for (int i = 0; i < 6; i++) {
    int cc = tid + i * 256;          // 0..1535
    int row = cc >> 4, c8 = (cc & 15) * 8;
    *(s8v*)&WL[row][c8] = *(const s8v*)&Wcb[(nbase + row) * 128 + c8];
  }
  if (tid < 96) bcs[tid] = bc[nbase + tid];
  __syncthreads();   // affine visible

  // pack x tile to bf16 LDS
  #pragma unroll
  for (int i = 0; i < 16; i++) {
    int c0 = (w + i * 4) * 2;
    ushort e0 = (ushort)f2bf(fmaf(va[i], sm_s[c0],     sm_t[c0]));
    ushort e1 = (ushort)f2bf(fmaf(vb[i], sm_s[c0 + 1], sm_t[c0 + 1]));
    *(uint*)&xn[lane][c0] = ((uint)e1 << 16) | e0;
  }
  __syncthreads();   // xn/WL visible

  int l15 = lane & 15, kh = lane >> 4;
  f4v acc[6];
  #pragma unroll
  for (int nt = 0; nt < 6; nt++) acc[nt] = (f4v){0.f, 0.f, 0.f, 0.f};
  #pragma unroll
  for (int ks = 0; ks < 4; ks++) {
    s8v a = *(s8v*)&xn[w * 16 + l15][ks * 32 + kh * 8];
    #pragma unroll
    for (int nt = 0; nt < 6; nt++) {
      s8v wf = *(s8v*)&WL[nt * 16 + l15][ks * 32 + kh * 8];
      if (nbase + nt * 16 < 256)    // q/k tile: swapped operands
        acc[nt] = __builtin_amdgcn_mfma_f32_16x16x32_bf16(wf, a, acc[nt], 0, 0, 0);
      else                           // v tile
        acc[nt] = __builtin_amdgcn_mfma_f32_16x16x32_bf16(a, wf, acc[nt], 0, 0, 0);
    }
  }
  #pragma unroll
  for (int nt = 0; nt < 6; nt++) {
    if (nbase + nt * 16 < 256) {
      // lane holds o = nbase+nt*16+kh*4+r, px = pbase+w*16+l15
      int ob  = nt * 16 + kh * 4;
      int o0i = nbase + ob;
      int hd  = (o0i & 127) >> 5, d0 = o0i & 31;
      int bh2 = b * 4 + hd;
      int px  = pbase + w * 16 + l15;
      short* dst = (o0i >> 7) ? kb : qb;
      ushort e0 = (ushort)f2bf(acc[nt][0] + bcs[ob + 0]);
      ushort e1 = (ushort)f2bf(acc[nt][1] + bcs[ob + 1]);
      ushort e2 = (ushort)f2bf(acc[nt][2] + bcs[ob + 2]);
      ushort e3 = (ushort)f2bf(acc[nt][3] + bcs[ob + 3]);
      uint2 pk = make_uint2(((uint)e1 << 16) | e0, ((uint)e3 << 16) | e2);
      *(uint2*)&dst[((size_t)bh2 * 4096 + px) * 32 + d0] = pk;
    } else {
      // lane holds o = nbase+nt*16+l15, px = pbase+w*16+kh*4+r
      int o   = nbase + nt * 16 + l15;
      int hd  = (o & 127) >> 5, d = o & 31;
      int bh2 = b * 4 + hd;
      int px0 = pbase + w * 16 + kh * 4;
      float bias = bcs[nt * 16 + l15];
      ushort s0 = (ushort)f2bf(acc[nt][0] + bias);
      ushort s1 = (ushort)f2bf(acc[nt][1] + bias);
      ushort s2 = (ushort)f2bf(acc[nt][2] + bias);
      ushort s3 = (ushort)f2bf(acc[nt][3] + bias);
      uint2 pk2 = make_uint2(((uint)s1 << 16) | s0, ((uint)s3 << 16) | s2);
      *(uint2*)&vtb[((size_t)bh2 * 32 + d) * 4096 + px0] = pk2;
    }
  }
}

// K3: MFMA neighborhood attention + fused out-projection, 2 query rows per block.
// Round-8 configuration verbatim (best measured): Wo_s in LDS (staging overlaps
// attention phase on its own buffer), separate tile buffer, 2 barriers.
__global__ __launch_bounds__(512) void k3_attn_proj(
    const short* __restrict__ qb, const short* __restrict__ kb, const short* __restrict__ vtb,
    const float* __restrict__ rpb, const short* __restrict__ WoB,
    const float* __restrict__ bo, float* __restrict__ out) {
  __shared__ ushort K_s[8][64][32];      // 32 KB
  __shared__ ushort VT_s[8][32][68];     // 34 KB
  __shared__ ushort P_s[8][16][40];      // 10 KB
  __shared__ ushort Wo_s[128][136];      // 34 KB
  __shared__ ushort tile_s[2][16][136];  // 8.5 KB
  __shared__ float  rpb_s[176];

  int lb    = blockIdx.x;           // 0..255
  int bh    = lb & 7;               // XCD swizzle: each XCD owns one bh
  int chunk = lb >> 3;              // 0..31
  int y0    = chunk * 2;
  int head  = bh & 3, b = bh >> 2;
  int tid   = threadIdx.x;
  int w     = __builtin_amdgcn_readfirstlane(tid >> 6);  // 0..7
  int lane  = tid & 63, l15 = lane & 15, kh = lane >> 4;
  int wsub  = w & 3, rsel = w >> 2;
  int y     = y0 + rsel;
  int ys0   = min(max(y0 - 3, 0), 57);
  int ysoff = min(max(y - 3, 0), 57) - ys0;   // 0 or 1

  // stage K window (8 rows x 64 col x 32 ch bf16)
  {
    const size_t kbase = (size_t)bh * 4096 * 32;
    #pragma unroll
    for (int i = 0; i < 4; i++) {
      int cc = tid + i * 512;
      int row = cc >> 8, rem = cc & 255;
      int col = rem >> 2, ch8 = (rem & 3) * 8;
      int yr = min(ys0 + row, 63);
      *(s8v*)&K_s[row][col][ch8] = *(const s8v*)&kb[kbase + (size_t)(yr * 64 + col) * 32 + ch8];
    }
  }
  // stage VT window (8 rows x 32 d x 64 px bf16)
  {
    const size_t vbase = (size_t)bh * 32 * 4096;
    #pragma unroll
    for (int i = 0; i < 4; i++) {
      int cc = tid + i * 512;
      int row = cc >> 8, rem = cc & 255;
      int d = rem >> 3, c8 = (rem & 7) * 8;
      int yr = min(ys0 + row, 63);
      *(s8v*)&VT_s[row][d][c8] = *(const s8v*)&vtb[vbase + (size_t)d * 4096 + yr * 64 + c8];
    }
  }
  // stage Wo (overlaps attention phase on its own buffer)
  #pragma unroll
  for (int i = 0; i < 4; i++) {
    int cc = tid + i * 512;
    int row = cc >> 4, c8 = (cc & 15) * 8;
    *(s8v*)&Wo_s[row][c8] = *(const s8v*)&WoB[row * 128 + c8];
  }
  if (tid < 169) rpb_s[tid] = rpb[head * 169 + tid];
  __syncthreads();

  int c0  = wsub * 8 + (wsub >> 1) * 8;   // strip col window start: 0,8,24,32
  int xq  = wsub * 16 + l15;              // query x
  int xs  = min(max(xq - 3, 0), 57);
  int pbw = 3 + max(3 - xq, 0) + min(60 - xq, 0);
  int pbh = 3 + max(3 - y, 0) + min(60 - y, 0);

  s8v qf = *(const s8v*)&qb[((size_t)bh * 4096 + y * 64 + xq) * 32 + kh * 8];

  int   bidx[8];
  float badd[8];
  #pragma unroll
  for (int j = 0; j < 8; ++j) {
    int cc = (j >> 2) * 16 + kh * 4 + (j & 3);
    int dx = c0 + cc - xs;
    bool valid = (dx >= 0) && (dx < 7);
    bidx[j] = pbw + min(max(dx, 0), 6);
    badd[j] = valid ? 0.f : -1e30f;
  }

  const f4v zero = {0.f, 0.f, 0.f, 0.f};
  f4v o0 = zero, o1 = zero;
  float ssum = 0.f;

  #pragma unroll
  for (int row = 0; row < 7; ++row) {
    int kr = ysoff + row;
    s8v ka0 = *(s8v*)&K_s[kr][c0 + l15][kh * 8];
    s8v ka1 = *(s8v*)&K_s[kr][c0 + 16 + l15][kh * 8];
    f4v lg0 = __builtin_amdgcn_mfma_f32_16x16x32_bf16(ka0, qf, zero, 0, 0, 0);
    f4v lg1 = __builtin_amdgcn_mfma_f32_16x16x32_bf16(ka1, qf, zero, 0, 0, 0);
    int rbase = (pbh + row) * 13;
    float p[8];
    #pragma unroll
    for (int j = 0; j < 4; ++j) {
      p[j]     = __expf(lg0[j] + rpb_s[rbase + bidx[j]]     + badd[j]);
      p[j + 4] = __expf(lg1[j] + rpb_s[rbase + bidx[j + 4]] + badd[j + 4]);
      ssum += p[j] + p[j + 4];
    }
    uint u0 = ((uint)(ushort)f2bf(p[1]) << 16) | (ushort)f2bf(p[0]);
    uint u1 = ((uint)(ushort)f2bf(p[3]) << 16) | (ushort)f2bf(p[2]);
    uint u2 = ((uint)(ushort)f2bf(p[5]) << 16) | (ushort)f2bf(p[4]);
    uint u3 = ((uint)(ushort)f2bf(p[7]) << 16) | (ushort)f2bf(p[6]);
    *(uint2*)&P_s[w][l15][kh * 4]      = make_uint2(u0, u1);
    *(uint2*)&P_s[w][l15][16 + kh * 4] = make_uint2(u2, u3);
    s8v pa  = *(s8v*)&P_s[w][l15][kh * 8];
    s8v vt0 = *(s8v*)&VT_s[kr][l15][c0 + kh * 8];
    s8v vt1 = *(s8v*)&VT_s[kr][16 + l15][c0 + kh * 8];
    o0 = __builtin_amdgcn_mfma_f32_16x16x32_bf16(pa, vt0, o0, 0, 0, 0);
    o1 = __builtin_amdgcn_mfma_f32_16x16x32_bf16(pa, vt1, o1, 0, 0, 0);
  }

  ssum += __shfl_xor(ssum, 16, 64);
  ssum += __shfl_xor(ssum, 32, 64);

  // write attention tile (own buffer -> no barrier needed before this)
  {
    int col = wsub * 4 + kh;
    #pragma unroll
    for (int r = 0; r < 4; ++r) {
      float sq = __builtin_bit_cast(float,
          __builtin_amdgcn_ds_bpermute((kh * 4 + r) << 2, __builtin_bit_cast(int, ssum)));
      float inv = 1.f / sq;
      tile_s[rsel][col][r * 32 + l15]      = (ushort)f2bf(o0[r] * inv);
      tile_s[rsel][col][r * 32 + 16 + l15] = (ushort)f2bf(o1[r] * inv);
    }
  }
  __syncthreads();

  // out-projection: wave (wsub,rsel) owns outputs o = wsub*32 + nt*16 + l15 for its row
  f4v acc2[2];
  acc2[0] = zero; acc2[1] = zero;
  #pragma unroll
  for (int ks = 0; ks < 4; ks++) {
    s8v a = *(s8v*)&tile_s[rsel][l15][ks * 32 + kh * 8];
    #pragma unroll
    for (int nt = 0; nt < 2; nt++) {
      s8v bf = *(s8v*)&Wo_s[wsub * 32 + nt * 16 + l15][ks * 32 + kh * 8];
      acc2[nt] = __builtin_amdgcn_mfma_f32_16x16x32_bf16(a, bf, acc2[nt], 0, 0, 0);
    }
  }
  int pxg = (head * 16 + (y >> 2)) * 64 + ((y & 3) << 4);
  #pragma unroll
  for (int nt = 0; nt < 2; nt++) {
    int o = wsub * 32 + nt * 16 + l15;
    float bias = bo[o];
    float4 val = make_float4(acc2[nt][0] + bias, acc2[nt][1] + bias,
                             acc2[nt][2] + bias, acc2[nt][3] + bias);
    *(float4*)&out[((size_t)b * 128 + o) * 4096 + pxg + kh * 4] = val;
  }
}

extern "C" void kernel_launch(void* const* d_in, const int* in_sizes, int n_in,
                              void* d_out, int out_size, void* d_ws, size_t ws_size,
                              hipStream_t stream) {
  (void)in_sizes; (void)n_in; (void)out_size; (void)ws_size;
  const float* x   = (const float*)d_in[0];
  const float* gw  = (const float*)d_in[1];
  const float* gb  = (const float*)d_in[2];
  const float* wq  = (const float*)d_in[3];
  const float* bq  = (const float*)d_in[4];
  const float* wk  = (const float*)d_in[5];
  const float* bk  = (const float*)d_in[6];
  const float* wv  = (const float*)d_in[7];
  const float* bv  = (const float*)d_in[8];
  const float* wo  = (const float*)d_in[9];
  const float* bo  = (const float*)d_in[10];
  const float* rpb = (const float*)d_in[11];
  float* ws     = (float*)d_ws;
  float* Spart  = ws + OFF_SP;
  float* S2part = ws + OFF_S2P;
  short* Wcb    = (short*)(ws + OFF_WCB);
  float* bc     = ws + OFF_BC;
  short* qb     = (short*)(ws + OFF_QB);
  short* kb     = (short*)(ws + OFF_KB);
  short* vtb    = (short*)(ws + OFF_VTB);
  short* WoB    = (short*)(ws + OFF_WOB);
  float* out    = (float*)d_out;

  hipLaunchKernelGGL(kP, dim3(320), dim3(256), 0, stream,
                     wq, bq, wk, bk, wv, bv, wo, x, Wcb, bc, WoB, Spart, S2part);
  hipLaunchKernelGGL(k2_qkv, dim3(512), dim3(256), 0, stream,
                     x, Spart, S2part, gw, gb, Wcb, bc, qb, kb, vtb);
  hipLaunchKernelGGL(k3_attn_proj, dim3(256), dim3(512), 0, stream,
                     qb, kb, vtb, rpb, WoB, bo, out);
}